// Round 15
// baseline (226.483 us; speedup 1.0000x reference)
//
#include <hip/hip_runtime.h>

#define N_NODES_C 100000
#define N_EDGES_C 1600000
#define NCHUNK 256                 // hist chunks
#define CHH (N_EDGES_C / NCHUNK)   // 6250
#define NPART 128                  // partition blocks (2 chunks each)
#define CHP (N_EDGES_C / NPART)    // 12500
#define BUCK_SH 7
#define BUCK_NODES 128
#define NB_BUCK 782                // ceil(100000 / 128)

typedef short short8 __attribute__((ext_vector_type(8)));
typedef float f32x4 __attribute__((ext_vector_type(4)));
typedef float f32x2 __attribute__((ext_vector_type(2)));

// float -> bf16 bits (RNE)
__device__ __forceinline__ short f2bf(float f) {
  unsigned u = __builtin_bit_cast(unsigned, f);
  unsigned r = (u + 0x7FFFu + ((u >> 16) & 1u)) >> 16;
  return (short)r;
}

// HW fp8 (OCP e4m3 on gfx950) conversions.
__device__ __forceinline__ unsigned char f32_to_fp8_hw(float x) {
  return (unsigned char)(__builtin_amdgcn_cvt_pk_fp8_f32(x, x, 0, false) & 0xFF);
}

// ---------------------------------------------------------------------------
// MFMA GEMM body: out[n][64] = in[n][K] @ W[K][64], fp32 in, fp8 out.
// ---------------------------------------------------------------------------
template <int K>
__device__ __forceinline__ void gemm64_body(
    int gblock, const float* __restrict__ in_, const float* __restrict__ W,
    unsigned char* __restrict__ out_, int n_rows) {
  constexpr int KS = K / 32;
  int wave = threadIdx.x >> 6;
  int lane = threadIdx.x & 63;
  int row0 = (gblock * 4 + wave) * 16;
  if (row0 >= n_rows) return;

  int lrow = lane & 15;
  int lk = (lane >> 4) * 8;

  short8 bfrag[KS][4];
#pragma unroll
  for (int ks = 0; ks < KS; ++ks)
#pragma unroll
    for (int nt = 0; nt < 4; ++nt) {
      short8 b;
#pragma unroll
      for (int j = 0; j < 8; ++j)
        b[j] = f2bf(W[(size_t)(ks * 32 + lk + j) * 64 + nt * 16 + lrow]);
      bfrag[ks][nt] = b;
    }

  int row = row0 + lrow;
  f32x4 acc[4] = {};
#pragma unroll
  for (int ks = 0; ks < KS; ++ks) {
    short8 a;
    const float* ip = in_ + (size_t)row * K + ks * 32 + lk;
    f32x4 v0 = *(const f32x4*)(ip);
    f32x4 v1 = *(const f32x4*)(ip + 4);
#pragma unroll
    for (int j = 0; j < 4; ++j) {
      a[j] = f2bf(v0[j]);
      a[4 + j] = f2bf(v1[j]);
    }
#pragma unroll
    for (int nt = 0; nt < 4; ++nt)
      acc[nt] = __builtin_amdgcn_mfma_f32_16x16x32_bf16(a, bfrag[ks][nt],
                                                        acc[nt], 0, 0, 0);
  }

  int crow = row0 + (lane >> 4) * 4;
#pragma unroll
  for (int nt = 0; nt < 4; ++nt) {
    int ocol = nt * 16 + lrow;
#pragma unroll
    for (int r = 0; r < 4; ++r)
      out_[(size_t)(crow + r) * 64 + ocol] = f32_to_fp8_hw(acc[nt][r]);
  }
}

// ---------------------------------------------------------------------------
// Fused: blocks [0, NCHUNK) = bucket histogram (LDS int atomics);
// blocks [NCHUNK, +gemm_grid) = GEMM1 (x@W1 -> hA fp8). Independent.
// ---------------------------------------------------------------------------
__global__ __launch_bounds__(256) void hist_gemm1_kernel(
    const int* __restrict__ dst, int* __restrict__ countsT,
    const float* __restrict__ x, const float* __restrict__ W1,
    unsigned char* __restrict__ hA, int n_rows) {
  __shared__ int lhist[NB_BUCK];
  int b = (int)blockIdx.x;
  if (b >= NCHUNK) {
    gemm64_body<128>(b - NCHUNK, x, W1, hA, n_rows);
    return;
  }
  for (int i = threadIdx.x; i < NB_BUCK; i += 256) lhist[i] = 0;
  __syncthreads();
  int beg = b * CHH, end = beg + CHH;
  for (int i = beg + (int)threadIdx.x; i < end; i += 256)
    atomicAdd(&lhist[((unsigned)dst[i]) >> BUCK_SH], 1);
  __syncthreads();
  for (int bb = threadIdx.x; bb < NB_BUCK; bb += 256)
    countsT[bb * NCHUNK + b] = lhist[bb];
}

// K1: per-bucket exclusive scan over NCHUNK=256 chunk counts (+ total).
__global__ __launch_bounds__(256) void scan_buckets_kernel(
    int* __restrict__ countsT, int* __restrict__ btot) {
  int b = blockIdx.x * 4 + (threadIdx.x >> 6);
  int lane = threadIdx.x & 63;
  if (b >= NB_BUCK) return;
  int4 v = *(const int4*)(countsT + b * NCHUNK + lane * 4);
  int s = v.x + v.y + v.z + v.w;
  int incl = s;
#pragma unroll
  for (int d = 1; d < 64; d <<= 1) {
    int t = __shfl_up(incl, d, 64);
    if (lane >= d) incl += t;
  }
  int excl = incl - s;
  int4 o;
  o.x = excl;
  o.y = excl + v.x;
  o.z = o.y + v.y;
  o.w = o.z + v.z;
  *(int4*)(countsT + b * NCHUNK + lane * 4) = o;
  if (lane == 63) btot[b] = incl;
}

// K2: exclusive scan of bucket totals -> bstart[0..NB_BUCK].
__global__ __launch_bounds__(1024) void scan_btot_kernel(
    const int* __restrict__ btot, int* __restrict__ bstart) {
  __shared__ int lds[1024];
  int t = threadIdx.x;
  int v = (t < NB_BUCK) ? btot[t] : 0;
  lds[t] = v;
  __syncthreads();
  for (int off = 1; off < 1024; off <<= 1) {
    int tv = (t >= off) ? lds[t - off] : 0;
    __syncthreads();
    lds[t] += tv;
    __syncthreads();
  }
  if (t < NB_BUCK) bstart[t] = lds[t] - v;
  if (t == NB_BUCK - 1) bstart[NB_BUCK] = lds[t];
}

// ---------------------------------------------------------------------------
// Partition (standalone, WIDE): 128 blocks x 1024 threads (16 waves) so the
// scatter phase has 2048 waves of latency-hiding. Runs stay 64B line-aligned.
// ---------------------------------------------------------------------------
__global__ __launch_bounds__(1024) void partition_kernel(
    const int* __restrict__ src, const int* __restrict__ dst,
    const int* __restrict__ offs /* countsT after K1 */,
    const int* __restrict__ bstart, unsigned* __restrict__ packed) {
  __shared__ int cur[NB_BUCK];
  int b = (int)blockIdx.x;
  for (int bb = threadIdx.x; bb < NB_BUCK; bb += 1024)
    cur[bb] = bstart[bb] + offs[bb * NCHUNK + 2 * b];
  __syncthreads();
  int beg = b * CHP, end = beg + CHP;
  for (int i = beg + (int)threadIdx.x; i < end; i += 1024) {
    int d = dst[i];
    int s = src[i];
    int bb = ((unsigned)d) >> BUCK_SH;
    int pos = atomicAdd(&cur[bb], 1);
    packed[pos] = ((unsigned)(d & (BUCK_NODES - 1)) << 17) | (unsigned)s;
  }
}

// ---------------------------------------------------------------------------
// Per-bucket counting sort -> dst-sorted col[] + row_ptr[] (global CSR).
// ---------------------------------------------------------------------------
__global__ __launch_bounds__(256) void sort_bucket_kernel(
    const unsigned* __restrict__ packed, const int* __restrict__ bstart,
    int* __restrict__ col, int* __restrict__ row_ptr, int n_nodes,
    int n_edges) {
  __shared__ int lhist[BUCK_NODES];
  __shared__ int lcur[BUCK_NODES];
  __shared__ int wsum0;
  int b = (int)blockIdx.x;
  int beg = bstart[b], end = bstart[b + 1];
  int t = (int)threadIdx.x;

  if (t < BUCK_NODES) lhist[t] = 0;
  __syncthreads();
  for (int e = beg + t; e < end; e += 256)
    atomicAdd(&lhist[packed[e] >> 17], 1);
  __syncthreads();

  int v = 0, incl = 0;
  if (t < BUCK_NODES) {
    v = lhist[t];
    incl = v;
#pragma unroll
    for (int d = 1; d < 64; d <<= 1) {
      int u = __shfl_up(incl, d, 64);
      if ((t & 63) >= d) incl += u;
    }
  }
  if (t == 63) wsum0 = incl;
  __syncthreads();
  if (t >= 64 && t < BUCK_NODES) incl += wsum0;
  if (t < BUCK_NODES) {
    int excl = incl - v;
    lcur[t] = excl;
    int node = b * BUCK_NODES + t;
    if (node < n_nodes) row_ptr[node] = beg + excl;
  }
  if (b == NB_BUCK - 1 && t == 0) row_ptr[n_nodes] = n_edges;
  __syncthreads();

  for (int e = beg + t; e < end; e += 256) {
    unsigned pe = packed[e];
    int ld = (int)(pe >> 17);
    int pos = beg + atomicAdd(&lcur[ld], 1);
    col[pos] = (int)(pe & 0x1FFFFu);
  }
}

// ---------------------------------------------------------------------------
// Agg inner (fp8 table, HW decode, nontemporal col stream).
// ---------------------------------------------------------------------------
__device__ __forceinline__ void agg_node(
    const unsigned char* __restrict__ h, const int* __restrict__ col, int beg,
    int end, int slot, int q, float& s0, float& s1, float& s2, float& s3) {
  s0 = s1 = s2 = s3 = 0.f;
  float t0 = 0.f, t1 = 0.f, t2 = 0.f, t3 = 0.f;
  int e = beg + slot;
  for (; e + 12 < end; e += 16) {
    int sa = __builtin_nontemporal_load(col + e);
    int sb = __builtin_nontemporal_load(col + e + 4);
    int sc = __builtin_nontemporal_load(col + e + 8);
    int sd = __builtin_nontemporal_load(col + e + 12);
    int ua = *(const int*)(h + (size_t)sa * 64 + q * 4);
    int ub = *(const int*)(h + (size_t)sb * 64 + q * 4);
    int uc = *(const int*)(h + (size_t)sc * 64 + q * 4);
    int ud = *(const int*)(h + (size_t)sd * 64 + q * 4);
    f32x2 al = __builtin_amdgcn_cvt_pk_f32_fp8(ua, false);
    f32x2 ah = __builtin_amdgcn_cvt_pk_f32_fp8(ua, true);
    f32x2 bl = __builtin_amdgcn_cvt_pk_f32_fp8(ub, false);
    f32x2 bh = __builtin_amdgcn_cvt_pk_f32_fp8(ub, true);
    f32x2 cl = __builtin_amdgcn_cvt_pk_f32_fp8(uc, false);
    f32x2 ch = __builtin_amdgcn_cvt_pk_f32_fp8(uc, true);
    f32x2 dl = __builtin_amdgcn_cvt_pk_f32_fp8(ud, false);
    f32x2 dh = __builtin_amdgcn_cvt_pk_f32_fp8(ud, true);
    s0 += al[0] + bl[0];
    s1 += al[1] + bl[1];
    s2 += ah[0] + bh[0];
    s3 += ah[1] + bh[1];
    t0 += cl[0] + dl[0];
    t1 += cl[1] + dl[1];
    t2 += ch[0] + dh[0];
    t3 += ch[1] + dh[1];
  }
  for (; e < end; e += 4) {
    int sa = __builtin_nontemporal_load(col + e);
    int ua = *(const int*)(h + (size_t)sa * 64 + q * 4);
    f32x2 al = __builtin_amdgcn_cvt_pk_f32_fp8(ua, false);
    f32x2 ah = __builtin_amdgcn_cvt_pk_f32_fp8(ua, true);
    s0 += al[0];
    s1 += al[1];
    s2 += ah[0];
    s3 += ah[1];
  }
  s0 += t0;
  s1 += t1;
  s2 += t2;
  s3 += t3;
  s0 += __shfl_xor(s0, 16);
  s1 += __shfl_xor(s1, 16);
  s2 += __shfl_xor(s2, 16);
  s3 += __shfl_xor(s3, 16);
  s0 += __shfl_xor(s0, 32);
  s1 += __shfl_xor(s1, 32);
  s2 += __shfl_xor(s2, 32);
  s3 += __shfl_xor(s3, 32);
}

// ---------------------------------------------------------------------------
// Fused agg + bias + ReLU + (row @ W) -> fp8. Block = 16 nodes, 4 waves.
// ---------------------------------------------------------------------------
__global__ __launch_bounds__(256) void agg_gemm_kernel(
    const unsigned char* __restrict__ h, const int* __restrict__ row_ptr,
    const int* __restrict__ col, const float* __restrict__ bias,
    const float* __restrict__ W, unsigned char* __restrict__ outg,
    int n_nodes) {
  __shared__ float rowbuf[16][68];
  int wid = threadIdx.x >> 6;
  int lane = threadIdx.x & 63;
  int slot = lane >> 4;
  int q = lane & 15;
  int nbase = blockIdx.x * 16;

#pragma unroll
  for (int n = 0; n < 4; ++n) {
    int ln = wid * 4 + n;
    int node = nbase + ln;
    float s0, s1, s2, s3;
    agg_node(h, col, row_ptr[node], row_ptr[node + 1], slot, q, s0, s1, s2, s3);
    if (lane < 16) {
      f32x4 r;
      r[0] = fmaxf(s0 + bias[q * 4 + 0], 0.f);
      r[1] = fmaxf(s1 + bias[q * 4 + 1], 0.f);
      r[2] = fmaxf(s2 + bias[q * 4 + 2], 0.f);
      r[3] = fmaxf(s3 + bias[q * 4 + 3], 0.f);
      *(f32x4*)&rowbuf[ln][q * 4] = r;
    }
  }
  __syncthreads();

  int lrow = lane & 15;
  int lk = (lane >> 4) * 8;
  f32x4 acc = {};
#pragma unroll
  for (int ks = 0; ks < 2; ++ks) {
    short8 a, bv;
#pragma unroll
    for (int j = 0; j < 8; ++j) a[j] = f2bf(rowbuf[lrow][ks * 32 + lk + j]);
#pragma unroll
    for (int j = 0; j < 8; ++j)
      bv[j] = f2bf(W[(size_t)(ks * 32 + lk + j) * 64 + wid * 16 + lrow]);
    acc = __builtin_amdgcn_mfma_f32_16x16x32_bf16(a, bv, acc, 0, 0, 0);
  }
  int crow = (lane >> 4) * 4;
#pragma unroll
  for (int r = 0; r < 4; ++r)
    __builtin_nontemporal_store(
        f32_to_fp8_hw(acc[r]),
        outg + (size_t)(nbase + crow + r) * 64 + wid * 16 + lrow);
}

// ---------------------------------------------------------------------------
// Final agg + bias + ReLU (fp32 out). Wave per node.
// ---------------------------------------------------------------------------
__global__ __launch_bounds__(256) void agg_final_kernel(
    const unsigned char* __restrict__ h, const int* __restrict__ row_ptr,
    const int* __restrict__ col, const float* __restrict__ bias,
    float* __restrict__ out, int n_nodes) {
  int node = blockIdx.x * 4 + (threadIdx.x >> 6);
  if (node >= n_nodes) return;
  int lane = threadIdx.x & 63;
  int slot = lane >> 4;
  int q = lane & 15;
  float s0, s1, s2, s3;
  agg_node(h, col, row_ptr[node], row_ptr[node + 1], slot, q, s0, s1, s2, s3);
  if (lane < 16) {
    f32x4 v;
    v[0] = fmaxf(s0 + bias[q * 4 + 0], 0.f);
    v[1] = fmaxf(s1 + bias[q * 4 + 1], 0.f);
    v[2] = fmaxf(s2 + bias[q * 4 + 2], 0.f);
    v[3] = fmaxf(s3 + bias[q * 4 + 3], 0.f);
    __builtin_nontemporal_store(v, (f32x4*)out + (size_t)node * 16 + q);
  }
}

extern "C" void kernel_launch(void* const* d_in, const int* in_sizes, int n_in,
                              void* d_out, int out_size, void* d_ws,
                              size_t ws_size, hipStream_t stream) {
  const float* x = (const float*)d_in[0];
  const int* src = (const int*)d_in[1];
  const int* dst = (const int*)d_in[2];
  const float* W1 = (const float*)d_in[3];
  const float* b1 = (const float*)d_in[4];
  const float* W2 = (const float*)d_in[5];
  const float* b2 = (const float*)d_in[6];
  const float* W3 = (const float*)d_in[7];
  const float* b3 = (const float*)d_in[8];
  float* out = (float*)d_out;

  const int N = N_NODES_C;
  const int E = N_EDGES_C;

  // Workspace layout (31 MB), as round 13.
  char* ws = (char*)d_ws;
  int* countsT = (int*)(ws + 0);
  int* btot = (int*)(ws + (1u << 20));
  int* bstart = (int*)(ws + (1u << 20) + (16u << 10));
  int* row_ptr = (int*)(ws + (2u << 20));
  unsigned* packed = (unsigned*)(ws + (3u << 20));
  int* col = (int*)(ws + (10u << 20));
  unsigned char* hA = (unsigned char*)(ws + (17u << 20));
  unsigned char* hB = (unsigned char*)(ws + (24u << 20));

  const int gemm_grid = (N + 63) / 64;  // 1563
  const int k1_grid = (NB_BUCK + 3) / 4;
  const int aggg_grid = N / 16;         // 6250
  const int aggf_grid = (N + 3) / 4;    // 25000

  // ---- CSR build; gemm1 overlapped with hist; wide partition ----
  hist_gemm1_kernel<<<NCHUNK + gemm_grid, 256, 0, stream>>>(dst, countsT, x,
                                                            W1, hA, N);
  scan_buckets_kernel<<<k1_grid, 256, 0, stream>>>(countsT, btot);
  scan_btot_kernel<<<1, 1024, 0, stream>>>(btot, bstart);
  partition_kernel<<<NPART, 1024, 0, stream>>>(src, dst, countsT, bstart,
                                               packed);
  sort_bucket_kernel<<<NB_BUCK, 256, 0, stream>>>(packed, bstart, col, row_ptr,
                                                  N, E);

  // ---- Layer 1 agg fused with gemm2: hB = fp8(relu(agg(hA)+b1) @ W2) ----
  agg_gemm_kernel<<<aggg_grid, 256, 0, stream>>>(hA, row_ptr, col, b1, W2, hB,
                                                 N);
  // ---- Layer 2 agg fused with gemm3: hA = fp8(relu(agg(hB)+b2) @ W3) ----
  agg_gemm_kernel<<<aggg_grid, 256, 0, stream>>>(hB, row_ptr, col, b2, W3, hA,
                                                 N);
  // ---- Layer 3 final: out = relu(agg(hA)+b3) (fp32) ----
  agg_final_kernel<<<aggf_grid, 256, 0, stream>>>(hA, row_ptr, col, b3, out, N);
}

// Round 16
// 204.795 us; speedup vs baseline: 1.1059x; 1.1059x over previous
//
#include <hip/hip_runtime.h>

#define N_NODES_C 100000
#define N_EDGES_C 1600000
#define NCHUNK 256                 // hist chunks
#define CHH (N_EDGES_C / NCHUNK)   // 6250
#define NPART 128                  // partition blocks (2 chunks each)
#define CHP (N_EDGES_C / NPART)    // 12500
#define BUCK_SH 7
#define BUCK_NODES 128
#define NB_BUCK 782                // ceil(100000 / 128)

typedef short short8 __attribute__((ext_vector_type(8)));
typedef float f32x4 __attribute__((ext_vector_type(4)));
typedef float f32x2 __attribute__((ext_vector_type(2)));

// float -> bf16 bits (RNE)
__device__ __forceinline__ short f2bf(float f) {
  unsigned u = __builtin_bit_cast(unsigned, f);
  unsigned r = (u + 0x7FFFu + ((u >> 16) & 1u)) >> 16;
  return (short)r;
}

// HW fp8 (OCP e4m3 on gfx950) conversions.
__device__ __forceinline__ unsigned char f32_to_fp8_hw(float x) {
  return (unsigned char)(__builtin_amdgcn_cvt_pk_fp8_f32(x, x, 0, false) & 0xFF);
}

// ---------------------------------------------------------------------------
// MFMA GEMM body: out[n][64] = in[n][K] @ W[K][64], fp32 in, fp8 out.
// ---------------------------------------------------------------------------
template <int K>
__device__ __forceinline__ void gemm64_body(
    int gblock, const float* __restrict__ in_, const float* __restrict__ W,
    unsigned char* __restrict__ out_, int n_rows) {
  constexpr int KS = K / 32;
  int wave = threadIdx.x >> 6;
  int lane = threadIdx.x & 63;
  int row0 = (gblock * 4 + wave) * 16;
  if (row0 >= n_rows) return;

  int lrow = lane & 15;
  int lk = (lane >> 4) * 8;

  short8 bfrag[KS][4];
#pragma unroll
  for (int ks = 0; ks < KS; ++ks)
#pragma unroll
    for (int nt = 0; nt < 4; ++nt) {
      short8 b;
#pragma unroll
      for (int j = 0; j < 8; ++j)
        b[j] = f2bf(W[(size_t)(ks * 32 + lk + j) * 64 + nt * 16 + lrow]);
      bfrag[ks][nt] = b;
    }

  int row = row0 + lrow;
  f32x4 acc[4] = {};
#pragma unroll
  for (int ks = 0; ks < KS; ++ks) {
    short8 a;
    const float* ip = in_ + (size_t)row * K + ks * 32 + lk;
    f32x4 v0 = *(const f32x4*)(ip);
    f32x4 v1 = *(const f32x4*)(ip + 4);
#pragma unroll
    for (int j = 0; j < 4; ++j) {
      a[j] = f2bf(v0[j]);
      a[4 + j] = f2bf(v1[j]);
    }
#pragma unroll
    for (int nt = 0; nt < 4; ++nt)
      acc[nt] = __builtin_amdgcn_mfma_f32_16x16x32_bf16(a, bfrag[ks][nt],
                                                        acc[nt], 0, 0, 0);
  }

  int crow = row0 + (lane >> 4) * 4;
#pragma unroll
  for (int nt = 0; nt < 4; ++nt) {
    int ocol = nt * 16 + lrow;
#pragma unroll
    for (int r = 0; r < 4; ++r)
      out_[(size_t)(crow + r) * 64 + ocol] = f32_to_fp8_hw(acc[nt][r]);
  }
}

// ---------------------------------------------------------------------------
// Fused: blocks [0, NCHUNK) = bucket histogram (LDS int atomics);
// blocks [NCHUNK, +gemm_grid) = GEMM1 (x@W1 -> hA fp8). Independent.
// ---------------------------------------------------------------------------
__global__ __launch_bounds__(256) void hist_gemm1_kernel(
    const int* __restrict__ dst, int* __restrict__ countsT,
    const float* __restrict__ x, const float* __restrict__ W1,
    unsigned char* __restrict__ hA, int n_rows) {
  __shared__ int lhist[NB_BUCK];
  int b = (int)blockIdx.x;
  if (b >= NCHUNK) {
    gemm64_body<128>(b - NCHUNK, x, W1, hA, n_rows);
    return;
  }
  for (int i = threadIdx.x; i < NB_BUCK; i += 256) lhist[i] = 0;
  __syncthreads();
  int beg = b * CHH, end = beg + CHH;
  for (int i = beg + (int)threadIdx.x; i < end; i += 256)
    atomicAdd(&lhist[((unsigned)dst[i]) >> BUCK_SH], 1);
  __syncthreads();
  for (int bb = threadIdx.x; bb < NB_BUCK; bb += 256)
    countsT[bb * NCHUNK + b] = lhist[bb];
}

// K1: per-bucket exclusive scan over NCHUNK=256 chunk counts (+ total).
__global__ __launch_bounds__(256) void scan_buckets_kernel(
    int* __restrict__ countsT, int* __restrict__ btot) {
  int b = blockIdx.x * 4 + (threadIdx.x >> 6);
  int lane = threadIdx.x & 63;
  if (b >= NB_BUCK) return;
  int4 v = *(const int4*)(countsT + b * NCHUNK + lane * 4);
  int s = v.x + v.y + v.z + v.w;
  int incl = s;
#pragma unroll
  for (int d = 1; d < 64; d <<= 1) {
    int t = __shfl_up(incl, d, 64);
    if (lane >= d) incl += t;
  }
  int excl = incl - s;
  int4 o;
  o.x = excl;
  o.y = excl + v.x;
  o.z = o.y + v.y;
  o.w = o.z + v.z;
  *(int4*)(countsT + b * NCHUNK + lane * 4) = o;
  if (lane == 63) btot[b] = incl;
}

// K2: exclusive scan of bucket totals -> bstart[0..NB_BUCK].
__global__ __launch_bounds__(1024) void scan_btot_kernel(
    const int* __restrict__ btot, int* __restrict__ bstart) {
  __shared__ int lds[1024];
  int t = threadIdx.x;
  int v = (t < NB_BUCK) ? btot[t] : 0;
  lds[t] = v;
  __syncthreads();
  for (int off = 1; off < 1024; off <<= 1) {
    int tv = (t >= off) ? lds[t - off] : 0;
    __syncthreads();
    lds[t] += tv;
    __syncthreads();
  }
  if (t < NB_BUCK) bstart[t] = lds[t] - v;
  if (t == NB_BUCK - 1) bstart[NB_BUCK] = lds[t];
}

// ---------------------------------------------------------------------------
// Partition (standalone, WIDE): 128 blocks x 1024 threads (16 waves) so the
// scatter phase has 2048 waves of latency-hiding. Runs stay 64B line-aligned.
// ---------------------------------------------------------------------------
__global__ __launch_bounds__(1024) void partition_kernel(
    const int* __restrict__ src, const int* __restrict__ dst,
    const int* __restrict__ offs /* countsT after K1 */,
    const int* __restrict__ bstart, unsigned* __restrict__ packed) {
  __shared__ int cur[NB_BUCK];
  int b = (int)blockIdx.x;
  for (int bb = threadIdx.x; bb < NB_BUCK; bb += 1024)
    cur[bb] = bstart[bb] + offs[bb * NCHUNK + 2 * b];
  __syncthreads();
  int beg = b * CHP, end = beg + CHP;
  for (int i = beg + (int)threadIdx.x; i < end; i += 1024) {
    int d = dst[i];
    int s = src[i];
    int bb = ((unsigned)d) >> BUCK_SH;
    int pos = atomicAdd(&cur[bb], 1);
    packed[pos] = ((unsigned)(d & (BUCK_NODES - 1)) << 17) | (unsigned)s;
  }
}

// ---------------------------------------------------------------------------
// Per-bucket counting sort -> dst-sorted col[] + row_ptr[] (global CSR).
// ---------------------------------------------------------------------------
__global__ __launch_bounds__(256) void sort_bucket_kernel(
    const unsigned* __restrict__ packed, const int* __restrict__ bstart,
    int* __restrict__ col, int* __restrict__ row_ptr, int n_nodes,
    int n_edges) {
  __shared__ int lhist[BUCK_NODES];
  __shared__ int lcur[BUCK_NODES];
  __shared__ int wsum0;
  int b = (int)blockIdx.x;
  int beg = bstart[b], end = bstart[b + 1];
  int t = (int)threadIdx.x;

  if (t < BUCK_NODES) lhist[t] = 0;
  __syncthreads();
  for (int e = beg + t; e < end; e += 256)
    atomicAdd(&lhist[packed[e] >> 17], 1);
  __syncthreads();

  int v = 0, incl = 0;
  if (t < BUCK_NODES) {
    v = lhist[t];
    incl = v;
#pragma unroll
    for (int d = 1; d < 64; d <<= 1) {
      int u = __shfl_up(incl, d, 64);
      if ((t & 63) >= d) incl += u;
    }
  }
  if (t == 63) wsum0 = incl;
  __syncthreads();
  if (t >= 64 && t < BUCK_NODES) incl += wsum0;
  if (t < BUCK_NODES) {
    int excl = incl - v;
    lcur[t] = excl;
    int node = b * BUCK_NODES + t;
    if (node < n_nodes) row_ptr[node] = beg + excl;
  }
  if (b == NB_BUCK - 1 && t == 0) row_ptr[n_nodes] = n_edges;
  __syncthreads();

  for (int e = beg + t; e < end; e += 256) {
    unsigned pe = packed[e];
    int ld = (int)(pe >> 17);
    int pos = beg + atomicAdd(&lcur[ld], 1);
    col[pos] = (int)(pe & 0x1FFFFu);
  }
}

// ---------------------------------------------------------------------------
// Agg inner (fp8 table, HW decode; plain loads — round-13 proven).
// lane = (edge slot 0..3) x (channel quad 0..15); lane loads uint (4 fp8 ch);
// decode = 2x v_cvt_pk_f32_fp8 per word.
// ---------------------------------------------------------------------------
__device__ __forceinline__ void agg_node(
    const unsigned char* __restrict__ h, const int* __restrict__ col, int beg,
    int end, int slot, int q, float& s0, float& s1, float& s2, float& s3) {
  s0 = s1 = s2 = s3 = 0.f;
  float t0 = 0.f, t1 = 0.f, t2 = 0.f, t3 = 0.f;
  int e = beg + slot;
  for (; e + 12 < end; e += 16) {
    int sa = col[e];
    int sb = col[e + 4];
    int sc = col[e + 8];
    int sd = col[e + 12];
    int ua = *(const int*)(h + (size_t)sa * 64 + q * 4);
    int ub = *(const int*)(h + (size_t)sb * 64 + q * 4);
    int uc = *(const int*)(h + (size_t)sc * 64 + q * 4);
    int ud = *(const int*)(h + (size_t)sd * 64 + q * 4);
    f32x2 al = __builtin_amdgcn_cvt_pk_f32_fp8(ua, false);
    f32x2 ah = __builtin_amdgcn_cvt_pk_f32_fp8(ua, true);
    f32x2 bl = __builtin_amdgcn_cvt_pk_f32_fp8(ub, false);
    f32x2 bh = __builtin_amdgcn_cvt_pk_f32_fp8(ub, true);
    f32x2 cl = __builtin_amdgcn_cvt_pk_f32_fp8(uc, false);
    f32x2 ch = __builtin_amdgcn_cvt_pk_f32_fp8(uc, true);
    f32x2 dl = __builtin_amdgcn_cvt_pk_f32_fp8(ud, false);
    f32x2 dh = __builtin_amdgcn_cvt_pk_f32_fp8(ud, true);
    s0 += al[0] + bl[0];
    s1 += al[1] + bl[1];
    s2 += ah[0] + bh[0];
    s3 += ah[1] + bh[1];
    t0 += cl[0] + dl[0];
    t1 += cl[1] + dl[1];
    t2 += ch[0] + dh[0];
    t3 += ch[1] + dh[1];
  }
  for (; e < end; e += 4) {
    int sa = col[e];
    int ua = *(const int*)(h + (size_t)sa * 64 + q * 4);
    f32x2 al = __builtin_amdgcn_cvt_pk_f32_fp8(ua, false);
    f32x2 ah = __builtin_amdgcn_cvt_pk_f32_fp8(ua, true);
    s0 += al[0];
    s1 += al[1];
    s2 += ah[0];
    s3 += ah[1];
  }
  s0 += t0;
  s1 += t1;
  s2 += t2;
  s3 += t3;
  s0 += __shfl_xor(s0, 16);
  s1 += __shfl_xor(s1, 16);
  s2 += __shfl_xor(s2, 16);
  s3 += __shfl_xor(s3, 16);
  s0 += __shfl_xor(s0, 32);
  s1 += __shfl_xor(s1, 32);
  s2 += __shfl_xor(s2, 32);
  s3 += __shfl_xor(s3, 32);
}

// ---------------------------------------------------------------------------
// Fused agg + bias + ReLU + (row @ W) -> fp8. Block = 16 nodes, 4 waves.
// ---------------------------------------------------------------------------
__global__ __launch_bounds__(256) void agg_gemm_kernel(
    const unsigned char* __restrict__ h, const int* __restrict__ row_ptr,
    const int* __restrict__ col, const float* __restrict__ bias,
    const float* __restrict__ W, unsigned char* __restrict__ outg,
    int n_nodes) {
  __shared__ float rowbuf[16][68];
  int wid = threadIdx.x >> 6;
  int lane = threadIdx.x & 63;
  int slot = lane >> 4;
  int q = lane & 15;
  int nbase = blockIdx.x * 16;

#pragma unroll
  for (int n = 0; n < 4; ++n) {
    int ln = wid * 4 + n;
    int node = nbase + ln;
    float s0, s1, s2, s3;
    agg_node(h, col, row_ptr[node], row_ptr[node + 1], slot, q, s0, s1, s2, s3);
    if (lane < 16) {
      f32x4 r;
      r[0] = fmaxf(s0 + bias[q * 4 + 0], 0.f);
      r[1] = fmaxf(s1 + bias[q * 4 + 1], 0.f);
      r[2] = fmaxf(s2 + bias[q * 4 + 2], 0.f);
      r[3] = fmaxf(s3 + bias[q * 4 + 3], 0.f);
      *(f32x4*)&rowbuf[ln][q * 4] = r;
    }
  }
  __syncthreads();

  int lrow = lane & 15;
  int lk = (lane >> 4) * 8;
  f32x4 acc = {};
#pragma unroll
  for (int ks = 0; ks < 2; ++ks) {
    short8 a, bv;
#pragma unroll
    for (int j = 0; j < 8; ++j) a[j] = f2bf(rowbuf[lrow][ks * 32 + lk + j]);
#pragma unroll
    for (int j = 0; j < 8; ++j)
      bv[j] = f2bf(W[(size_t)(ks * 32 + lk + j) * 64 + wid * 16 + lrow]);
    acc = __builtin_amdgcn_mfma_f32_16x16x32_bf16(a, bv, acc, 0, 0, 0);
  }
  int crow = (lane >> 4) * 4;
#pragma unroll
  for (int r = 0; r < 4; ++r)
    outg[(size_t)(nbase + crow + r) * 64 + wid * 16 + lrow] =
        f32_to_fp8_hw(acc[r]);
}

// ---------------------------------------------------------------------------
// Final agg + bias + ReLU (fp32 out). Wave per node.
// ---------------------------------------------------------------------------
__global__ __launch_bounds__(256) void agg_final_kernel(
    const unsigned char* __restrict__ h, const int* __restrict__ row_ptr,
    const int* __restrict__ col, const float* __restrict__ bias,
    float* __restrict__ out, int n_nodes) {
  int node = blockIdx.x * 4 + (threadIdx.x >> 6);
  if (node >= n_nodes) return;
  int lane = threadIdx.x & 63;
  int slot = lane >> 4;
  int q = lane & 15;
  float s0, s1, s2, s3;
  agg_node(h, col, row_ptr[node], row_ptr[node + 1], slot, q, s0, s1, s2, s3);
  if (lane < 16) {
    float4 v;
    v.x = fmaxf(s0 + bias[q * 4 + 0], 0.f);
    v.y = fmaxf(s1 + bias[q * 4 + 1], 0.f);
    v.z = fmaxf(s2 + bias[q * 4 + 2], 0.f);
    v.w = fmaxf(s3 + bias[q * 4 + 3], 0.f);
    ((float4*)out)[(size_t)node * 16 + q] = v;
  }
}

extern "C" void kernel_launch(void* const* d_in, const int* in_sizes, int n_in,
                              void* d_out, int out_size, void* d_ws,
                              size_t ws_size, hipStream_t stream) {
  const float* x = (const float*)d_in[0];
  const int* src = (const int*)d_in[1];
  const int* dst = (const int*)d_in[2];
  const float* W1 = (const float*)d_in[3];
  const float* b1 = (const float*)d_in[4];
  const float* W2 = (const float*)d_in[5];
  const float* b2 = (const float*)d_in[6];
  const float* W3 = (const float*)d_in[7];
  const float* b3 = (const float*)d_in[8];
  float* out = (float*)d_out;

  const int N = N_NODES_C;
  const int E = N_EDGES_C;

  // Workspace layout (31 MB), as round 13.
  char* ws = (char*)d_ws;
  int* countsT = (int*)(ws + 0);
  int* btot = (int*)(ws + (1u << 20));
  int* bstart = (int*)(ws + (1u << 20) + (16u << 10));
  int* row_ptr = (int*)(ws + (2u << 20));
  unsigned* packed = (unsigned*)(ws + (3u << 20));
  int* col = (int*)(ws + (10u << 20));
  unsigned char* hA = (unsigned char*)(ws + (17u << 20));
  unsigned char* hB = (unsigned char*)(ws + (24u << 20));

  const int gemm_grid = (N + 63) / 64;  // 1563
  const int k1_grid = (NB_BUCK + 3) / 4;
  const int aggg_grid = N / 16;         // 6250
  const int aggf_grid = (N + 3) / 4;    // 25000

  // ---- CSR build; gemm1 overlapped with hist; wide partition ----
  hist_gemm1_kernel<<<NCHUNK + gemm_grid, 256, 0, stream>>>(dst, countsT, x,
                                                            W1, hA, N);
  scan_buckets_kernel<<<k1_grid, 256, 0, stream>>>(countsT, btot);
  scan_btot_kernel<<<1, 1024, 0, stream>>>(btot, bstart);
  partition_kernel<<<NPART, 1024, 0, stream>>>(src, dst, countsT, bstart,
                                               packed);
  sort_bucket_kernel<<<NB_BUCK, 256, 0, stream>>>(packed, bstart, col, row_ptr,
                                                  N, E);

  // ---- Layer 1 agg fused with gemm2: hB = fp8(relu(agg(hA)+b1) @ W2) ----
  agg_gemm_kernel<<<aggg_grid, 256, 0, stream>>>(hA, row_ptr, col, b1, W2, hB,
                                                 N);
  // ---- Layer 2 agg fused with gemm3: hA = fp8(relu(agg(hB)+b2) @ W3) ----
  agg_gemm_kernel<<<aggg_grid, 256, 0, stream>>>(hB, row_ptr, col, b2, W3, hA,
                                                 N);
  // ---- Layer 3 final: out = relu(agg(hA)+b3) (fp32) ----
  agg_final_kernel<<<aggf_grid, 256, 0, stream>>>(hA, row_ptr, col, b3, out, N);
}

// Round 17
// 190.100 us; speedup vs baseline: 1.1914x; 1.0773x over previous
//
#include <hip/hip_runtime.h>

#define N_NODES_C 100000
#define N_EDGES_C 1600000
#define NCHUNK 256                 // hist chunks
#define CHH (N_EDGES_C / NCHUNK)   // 6250
#define NPART 128                  // partition blocks (2 chunks each)
#define CHP (N_EDGES_C / NPART)    // 12500
#define BUCK_SH 7
#define BUCK_NODES 128
#define NB_BUCK 782                // ceil(100000 / 128)

typedef short short8 __attribute__((ext_vector_type(8)));
typedef float f32x4 __attribute__((ext_vector_type(4)));
typedef float f32x2 __attribute__((ext_vector_type(2)));

// float -> bf16 bits (RNE)
__device__ __forceinline__ short f2bf(float f) {
  unsigned u = __builtin_bit_cast(unsigned, f);
  unsigned r = (u + 0x7FFFu + ((u >> 16) & 1u)) >> 16;
  return (short)r;
}

// HW fp8 (OCP e4m3 on gfx950) conversions.
__device__ __forceinline__ unsigned char f32_to_fp8_hw(float x) {
  return (unsigned char)(__builtin_amdgcn_cvt_pk_fp8_f32(x, x, 0, false) & 0xFF);
}

// ---------------------------------------------------------------------------
// MFMA GEMM body: out[n][64] = in[n][K] @ W[K][64], fp32 in, fp8 out.
// ---------------------------------------------------------------------------
template <int K>
__device__ __forceinline__ void gemm64_body(
    int gblock, const float* __restrict__ in_, const float* __restrict__ W,
    unsigned char* __restrict__ out_, int n_rows) {
  constexpr int KS = K / 32;
  int wave = threadIdx.x >> 6;
  int lane = threadIdx.x & 63;
  int row0 = (gblock * 4 + wave) * 16;
  if (row0 >= n_rows) return;

  int lrow = lane & 15;
  int lk = (lane >> 4) * 8;

  short8 bfrag[KS][4];
#pragma unroll
  for (int ks = 0; ks < KS; ++ks)
#pragma unroll
    for (int nt = 0; nt < 4; ++nt) {
      short8 b;
#pragma unroll
      for (int j = 0; j < 8; ++j)
        b[j] = f2bf(W[(size_t)(ks * 32 + lk + j) * 64 + nt * 16 + lrow]);
      bfrag[ks][nt] = b;
    }

  int row = row0 + lrow;
  f32x4 acc[4] = {};
#pragma unroll
  for (int ks = 0; ks < KS; ++ks) {
    short8 a;
    const float* ip = in_ + (size_t)row * K + ks * 32 + lk;
    f32x4 v0 = *(const f32x4*)(ip);
    f32x4 v1 = *(const f32x4*)(ip + 4);
#pragma unroll
    for (int j = 0; j < 4; ++j) {
      a[j] = f2bf(v0[j]);
      a[4 + j] = f2bf(v1[j]);
    }
#pragma unroll
    for (int nt = 0; nt < 4; ++nt)
      acc[nt] = __builtin_amdgcn_mfma_f32_16x16x32_bf16(a, bfrag[ks][nt],
                                                        acc[nt], 0, 0, 0);
  }

  int crow = row0 + (lane >> 4) * 4;
#pragma unroll
  for (int nt = 0; nt < 4; ++nt) {
    int ocol = nt * 16 + lrow;
#pragma unroll
    for (int r = 0; r < 4; ++r)
      out_[(size_t)(crow + r) * 64 + ocol] = f32_to_fp8_hw(acc[nt][r]);
  }
}

// ---------------------------------------------------------------------------
// Fused: blocks [0, NCHUNK) = bucket histogram (LDS int atomics);
// blocks [NCHUNK, +gemm_grid) = GEMM1 (x@W1 -> hA fp8). Independent.
// ---------------------------------------------------------------------------
__global__ __launch_bounds__(256) void hist_gemm1_kernel(
    const int* __restrict__ dst, int* __restrict__ countsT,
    const float* __restrict__ x, const float* __restrict__ W1,
    unsigned char* __restrict__ hA, int n_rows) {
  __shared__ int lhist[NB_BUCK];
  int b = (int)blockIdx.x;
  if (b >= NCHUNK) {
    gemm64_body<128>(b - NCHUNK, x, W1, hA, n_rows);
    return;
  }
  for (int i = threadIdx.x; i < NB_BUCK; i += 256) lhist[i] = 0;
  __syncthreads();
  int beg = b * CHH, end = beg + CHH;
  for (int i = beg + (int)threadIdx.x; i < end; i += 256)
    atomicAdd(&lhist[((unsigned)dst[i]) >> BUCK_SH], 1);
  __syncthreads();
  for (int bb = threadIdx.x; bb < NB_BUCK; bb += 256)
    countsT[bb * NCHUNK + b] = lhist[bb];
}

// K1: per-bucket exclusive scan over NCHUNK=256 chunk counts (+ total).
__global__ __launch_bounds__(256) void scan_buckets_kernel(
    int* __restrict__ countsT, int* __restrict__ btot) {
  int b = blockIdx.x * 4 + (threadIdx.x >> 6);
  int lane = threadIdx.x & 63;
  if (b >= NB_BUCK) return;
  int4 v = *(const int4*)(countsT + b * NCHUNK + lane * 4);
  int s = v.x + v.y + v.z + v.w;
  int incl = s;
#pragma unroll
  for (int d = 1; d < 64; d <<= 1) {
    int t = __shfl_up(incl, d, 64);
    if (lane >= d) incl += t;
  }
  int excl = incl - s;
  int4 o;
  o.x = excl;
  o.y = excl + v.x;
  o.z = o.y + v.y;
  o.w = o.z + v.z;
  *(int4*)(countsT + b * NCHUNK + lane * 4) = o;
  if (lane == 63) btot[b] = incl;
}

// K2: exclusive scan of bucket totals -> bstart[0..NB_BUCK].
__global__ __launch_bounds__(1024) void scan_btot_kernel(
    const int* __restrict__ btot, int* __restrict__ bstart) {
  __shared__ int lds[1024];
  int t = threadIdx.x;
  int v = (t < NB_BUCK) ? btot[t] : 0;
  lds[t] = v;
  __syncthreads();
  for (int off = 1; off < 1024; off <<= 1) {
    int tv = (t >= off) ? lds[t - off] : 0;
    __syncthreads();
    lds[t] += tv;
    __syncthreads();
  }
  if (t < NB_BUCK) bstart[t] = lds[t] - v;
  if (t == NB_BUCK - 1) bstart[NB_BUCK] = lds[t];
}

// ---------------------------------------------------------------------------
// Partition (standalone, WIDE): 128 blocks x 1024 threads.
// ---------------------------------------------------------------------------
__global__ __launch_bounds__(1024) void partition_kernel(
    const int* __restrict__ src, const int* __restrict__ dst,
    const int* __restrict__ offs /* countsT after K1 */,
    const int* __restrict__ bstart, unsigned* __restrict__ packed) {
  __shared__ int cur[NB_BUCK];
  int b = (int)blockIdx.x;
  for (int bb = threadIdx.x; bb < NB_BUCK; bb += 1024)
    cur[bb] = bstart[bb] + offs[bb * NCHUNK + 2 * b];
  __syncthreads();
  int beg = b * CHP, end = beg + CHP;
  for (int i = beg + (int)threadIdx.x; i < end; i += 1024) {
    int d = dst[i];
    int s = src[i];
    int bb = ((unsigned)d) >> BUCK_SH;
    int pos = atomicAdd(&cur[bb], 1);
    packed[pos] = ((unsigned)(d & (BUCK_NODES - 1)) << 17) | (unsigned)s;
  }
}

// ---------------------------------------------------------------------------
// Per-bucket counting sort -> dst-sorted col[] + row_ptr[] (global CSR).
// ---------------------------------------------------------------------------
__global__ __launch_bounds__(256) void sort_bucket_kernel(
    const unsigned* __restrict__ packed, const int* __restrict__ bstart,
    int* __restrict__ col, int* __restrict__ row_ptr, int n_nodes,
    int n_edges) {
  __shared__ int lhist[BUCK_NODES];
  __shared__ int lcur[BUCK_NODES];
  __shared__ int wsum0;
  int b = (int)blockIdx.x;
  int beg = bstart[b], end = bstart[b + 1];
  int t = (int)threadIdx.x;

  if (t < BUCK_NODES) lhist[t] = 0;
  __syncthreads();
  for (int e = beg + t; e < end; e += 256)
    atomicAdd(&lhist[packed[e] >> 17], 1);
  __syncthreads();

  int v = 0, incl = 0;
  if (t < BUCK_NODES) {
    v = lhist[t];
    incl = v;
#pragma unroll
    for (int d = 1; d < 64; d <<= 1) {
      int u = __shfl_up(incl, d, 64);
      if ((t & 63) >= d) incl += u;
    }
  }
  if (t == 63) wsum0 = incl;
  __syncthreads();
  if (t >= 64 && t < BUCK_NODES) incl += wsum0;
  if (t < BUCK_NODES) {
    int excl = incl - v;
    lcur[t] = excl;
    int node = b * BUCK_NODES + t;
    if (node < n_nodes) row_ptr[node] = beg + excl;
  }
  if (b == NB_BUCK - 1 && t == 0) row_ptr[n_nodes] = n_edges;
  __syncthreads();

  for (int e = beg + t; e < end; e += 256) {
    unsigned pe = packed[e];
    int ld = (int)(pe >> 17);
    int pos = beg + atomicAdd(&lcur[ld], 1);
    col[pos] = (int)(pe & 0x1FFFFu);
  }
}

// ---------------------------------------------------------------------------
// Agg inner, 8-slot layout: lane = (edge slot 0..7) x (channel octet 0..7).
// Each lane loads uint2 (8B = 8 fp8 ch); ONE wave instruction serves 8 edges
// (vs 4 before) -> half the VMEM gather instructions per edge. Decode VALU
// per lane unchanged (16B/lane per 16-edge iter). Reduce: xor 8, 16, 32.
// Accumulates 8 channels (8q..8q+7) in s0..s7.
// ---------------------------------------------------------------------------
__device__ __forceinline__ void agg_node8(
    const unsigned char* __restrict__ h, const int* __restrict__ col, int beg,
    int end, int slot, int q, float& s0, float& s1, float& s2, float& s3,
    float& s4, float& s5, float& s6, float& s7) {
  s0 = s1 = s2 = s3 = s4 = s5 = s6 = s7 = 0.f;
  float t0 = 0.f, t1 = 0.f, t2 = 0.f, t3 = 0.f;
  float t4 = 0.f, t5 = 0.f, t6 = 0.f, t7 = 0.f;
  int e = beg + slot;
  // 16 edges/iter: 2 independent uint2 gathers per lane
  for (; e + 8 < end; e += 16) {
    int sa = col[e];
    int sb = col[e + 8];
    uint2 ua = *(const uint2*)(h + (size_t)sa * 64 + q * 8);
    uint2 ub = *(const uint2*)(h + (size_t)sb * 64 + q * 8);
    f32x2 a0 = __builtin_amdgcn_cvt_pk_f32_fp8((int)ua.x, false);
    f32x2 a1 = __builtin_amdgcn_cvt_pk_f32_fp8((int)ua.x, true);
    f32x2 a2 = __builtin_amdgcn_cvt_pk_f32_fp8((int)ua.y, false);
    f32x2 a3 = __builtin_amdgcn_cvt_pk_f32_fp8((int)ua.y, true);
    f32x2 b0 = __builtin_amdgcn_cvt_pk_f32_fp8((int)ub.x, false);
    f32x2 b1 = __builtin_amdgcn_cvt_pk_f32_fp8((int)ub.x, true);
    f32x2 b2 = __builtin_amdgcn_cvt_pk_f32_fp8((int)ub.y, false);
    f32x2 b3 = __builtin_amdgcn_cvt_pk_f32_fp8((int)ub.y, true);
    s0 += a0[0];
    s1 += a0[1];
    s2 += a1[0];
    s3 += a1[1];
    s4 += a2[0];
    s5 += a2[1];
    s6 += a3[0];
    s7 += a3[1];
    t0 += b0[0];
    t1 += b0[1];
    t2 += b1[0];
    t3 += b1[1];
    t4 += b2[0];
    t5 += b2[1];
    t6 += b3[0];
    t7 += b3[1];
  }
  for (; e < end; e += 8) {
    int sa = col[e];
    uint2 ua = *(const uint2*)(h + (size_t)sa * 64 + q * 8);
    f32x2 a0 = __builtin_amdgcn_cvt_pk_f32_fp8((int)ua.x, false);
    f32x2 a1 = __builtin_amdgcn_cvt_pk_f32_fp8((int)ua.x, true);
    f32x2 a2 = __builtin_amdgcn_cvt_pk_f32_fp8((int)ua.y, false);
    f32x2 a3 = __builtin_amdgcn_cvt_pk_f32_fp8((int)ua.y, true);
    s0 += a0[0];
    s1 += a0[1];
    s2 += a1[0];
    s3 += a1[1];
    s4 += a2[0];
    s5 += a2[1];
    s6 += a3[0];
    s7 += a3[1];
  }
  s0 += t0;
  s1 += t1;
  s2 += t2;
  s3 += t3;
  s4 += t4;
  s5 += t5;
  s6 += t6;
  s7 += t7;
#pragma unroll
  for (int d = 8; d <= 32; d <<= 1) {
    s0 += __shfl_xor(s0, d);
    s1 += __shfl_xor(s1, d);
    s2 += __shfl_xor(s2, d);
    s3 += __shfl_xor(s3, d);
    s4 += __shfl_xor(s4, d);
    s5 += __shfl_xor(s5, d);
    s6 += __shfl_xor(s6, d);
    s7 += __shfl_xor(s7, d);
  }
}

// ---------------------------------------------------------------------------
// Fused agg + bias + ReLU + (row @ W) -> fp8. Block = 16 nodes, 4 waves.
// ---------------------------------------------------------------------------
__global__ __launch_bounds__(256) void agg_gemm_kernel(
    const unsigned char* __restrict__ h, const int* __restrict__ row_ptr,
    const int* __restrict__ col, const float* __restrict__ bias,
    const float* __restrict__ W, unsigned char* __restrict__ outg,
    int n_nodes) {
  __shared__ float rowbuf[16][68];
  int wid = threadIdx.x >> 6;
  int lane = threadIdx.x & 63;
  int slot = lane >> 3;
  int q = lane & 7;
  int nbase = blockIdx.x * 16;

#pragma unroll
  for (int n = 0; n < 4; ++n) {
    int ln = wid * 4 + n;
    int node = nbase + ln;
    float s0, s1, s2, s3, s4, s5, s6, s7;
    agg_node8(h, col, row_ptr[node], row_ptr[node + 1], slot, q, s0, s1, s2,
              s3, s4, s5, s6, s7);
    if (lane < 8) {
      f32x4 r0, r1;
      r0[0] = fmaxf(s0 + bias[q * 8 + 0], 0.f);
      r0[1] = fmaxf(s1 + bias[q * 8 + 1], 0.f);
      r0[2] = fmaxf(s2 + bias[q * 8 + 2], 0.f);
      r0[3] = fmaxf(s3 + bias[q * 8 + 3], 0.f);
      r1[0] = fmaxf(s4 + bias[q * 8 + 4], 0.f);
      r1[1] = fmaxf(s5 + bias[q * 8 + 5], 0.f);
      r1[2] = fmaxf(s6 + bias[q * 8 + 6], 0.f);
      r1[3] = fmaxf(s7 + bias[q * 8 + 7], 0.f);
      *(f32x4*)&rowbuf[ln][q * 8] = r0;
      *(f32x4*)&rowbuf[ln][q * 8 + 4] = r1;
    }
  }
  __syncthreads();

  int lrow = lane & 15;
  int lk = (lane >> 4) * 8;
  f32x4 acc = {};
#pragma unroll
  for (int ks = 0; ks < 2; ++ks) {
    short8 a, bv;
#pragma unroll
    for (int j = 0; j < 8; ++j) a[j] = f2bf(rowbuf[lrow][ks * 32 + lk + j]);
#pragma unroll
    for (int j = 0; j < 8; ++j)
      bv[j] = f2bf(W[(size_t)(ks * 32 + lk + j) * 64 + wid * 16 + lrow]);
    acc = __builtin_amdgcn_mfma_f32_16x16x32_bf16(a, bv, acc, 0, 0, 0);
  }
  int crow = (lane >> 4) * 4;
#pragma unroll
  for (int r = 0; r < 4; ++r)
    outg[(size_t)(nbase + crow + r) * 64 + wid * 16 + lrow] =
        f32_to_fp8_hw(acc[r]);
}

// ---------------------------------------------------------------------------
// Final agg + bias + ReLU (fp32 out). Wave per node.
// ---------------------------------------------------------------------------
__global__ __launch_bounds__(256) void agg_final_kernel(
    const unsigned char* __restrict__ h, const int* __restrict__ row_ptr,
    const int* __restrict__ col, const float* __restrict__ bias,
    float* __restrict__ out, int n_nodes) {
  int node = blockIdx.x * 4 + (threadIdx.x >> 6);
  if (node >= n_nodes) return;
  int lane = threadIdx.x & 63;
  int slot = lane >> 3;
  int q = lane & 7;
  float s0, s1, s2, s3, s4, s5, s6, s7;
  agg_node8(h, col, row_ptr[node], row_ptr[node + 1], slot, q, s0, s1, s2, s3,
            s4, s5, s6, s7);
  if (lane < 8) {
    float4 v0, v1;
    v0.x = fmaxf(s0 + bias[q * 8 + 0], 0.f);
    v0.y = fmaxf(s1 + bias[q * 8 + 1], 0.f);
    v0.z = fmaxf(s2 + bias[q * 8 + 2], 0.f);
    v0.w = fmaxf(s3 + bias[q * 8 + 3], 0.f);
    v1.x = fmaxf(s4 + bias[q * 8 + 4], 0.f);
    v1.y = fmaxf(s5 + bias[q * 8 + 5], 0.f);
    v1.z = fmaxf(s6 + bias[q * 8 + 6], 0.f);
    v1.w = fmaxf(s7 + bias[q * 8 + 7], 0.f);
    ((float4*)out)[(size_t)node * 16 + q * 2] = v0;
    ((float4*)out)[(size_t)node * 16 + q * 2 + 1] = v1;
  }
}

extern "C" void kernel_launch(void* const* d_in, const int* in_sizes, int n_in,
                              void* d_out, int out_size, void* d_ws,
                              size_t ws_size, hipStream_t stream) {
  const float* x = (const float*)d_in[0];
  const int* src = (const int*)d_in[1];
  const int* dst = (const int*)d_in[2];
  const float* W1 = (const float*)d_in[3];
  const float* b1 = (const float*)d_in[4];
  const float* W2 = (const float*)d_in[5];
  const float* b2 = (const float*)d_in[6];
  const float* W3 = (const float*)d_in[7];
  const float* b3 = (const float*)d_in[8];
  float* out = (float*)d_out;

  const int N = N_NODES_C;
  const int E = N_EDGES_C;

  // Workspace layout (31 MB), as round 13.
  char* ws = (char*)d_ws;
  int* countsT = (int*)(ws + 0);
  int* btot = (int*)(ws + (1u << 20));
  int* bstart = (int*)(ws + (1u << 20) + (16u << 10));
  int* row_ptr = (int*)(ws + (2u << 20));
  unsigned* packed = (unsigned*)(ws + (3u << 20));
  int* col = (int*)(ws + (10u << 20));
  unsigned char* hA = (unsigned char*)(ws + (17u << 20));
  unsigned char* hB = (unsigned char*)(ws + (24u << 20));

  const int gemm_grid = (N + 63) / 64;  // 1563
  const int k1_grid = (NB_BUCK + 3) / 4;
  const int aggg_grid = N / 16;         // 6250
  const int aggf_grid = (N + 3) / 4;    // 25000

  // ---- CSR build; gemm1 overlapped with hist; wide partition ----
  hist_gemm1_kernel<<<NCHUNK + gemm_grid, 256, 0, stream>>>(dst, countsT, x,
                                                            W1, hA, N);
  scan_buckets_kernel<<<k1_grid, 256, 0, stream>>>(countsT, btot);
  scan_btot_kernel<<<1, 1024, 0, stream>>>(btot, bstart);
  partition_kernel<<<NPART, 1024, 0, stream>>>(src, dst, countsT, bstart,
                                               packed);
  sort_bucket_kernel<<<NB_BUCK, 256, 0, stream>>>(packed, bstart, col, row_ptr,
                                                  N, E);

  // ---- Layer 1 agg fused with gemm2: hB = fp8(relu(agg(hA)+b1) @ W2) ----
  agg_gemm_kernel<<<aggg_grid, 256, 0, stream>>>(hA, row_ptr, col, b1, W2, hB,
                                                 N);
  // ---- Layer 2 agg fused with gemm3: hA = fp8(relu(agg(hB)+b2) @ W3) ----
  agg_gemm_kernel<<<aggg_grid, 256, 0, stream>>>(hB, row_ptr, col, b2, W3, hA,
                                                 N);
  // ---- Layer 3 final: out = relu(agg(hA)+b3) (fp32) ----
  agg_final_kernel<<<aggf_grid, 256, 0, stream>>>(hA, row_ptr, col, b3, out, N);
}

// Round 18
// 176.324 us; speedup vs baseline: 1.2845x; 1.0781x over previous
//
#include <hip/hip_runtime.h>

#define N_NODES_C 100000
#define N_EDGES_C 1600000
#define NCHUNK 256                 // hist chunks
#define CHH (N_EDGES_C / NCHUNK)   // 6250
#define NPART 128                  // partition blocks (2 chunks each)
#define CHP (N_EDGES_C / NPART)    // 12500
#define BUCK_SH 7
#define BUCK_NODES 128
#define NB_BUCK 782                // ceil(100000 / 128)

typedef short short8 __attribute__((ext_vector_type(8)));
typedef float f32x4 __attribute__((ext_vector_type(4)));
typedef float f32x2 __attribute__((ext_vector_type(2)));

// float -> bf16 bits (RNE)
__device__ __forceinline__ short f2bf(float f) {
  unsigned u = __builtin_bit_cast(unsigned, f);
  unsigned r = (u + 0x7FFFu + ((u >> 16) & 1u)) >> 16;
  return (short)r;
}

// HW fp8 (OCP e4m3 on gfx950) conversions.
__device__ __forceinline__ unsigned char f32_to_fp8_hw(float x) {
  return (unsigned char)(__builtin_amdgcn_cvt_pk_fp8_f32(x, x, 0, false) & 0xFF);
}

// ---------------------------------------------------------------------------
// MFMA GEMM body: out[n][64] = in[n][K] @ W[K][64], fp32 in, fp8 out.
// ---------------------------------------------------------------------------
template <int K>
__device__ __forceinline__ void gemm64_body(
    int gblock, const float* __restrict__ in_, const float* __restrict__ W,
    unsigned char* __restrict__ out_, int n_rows) {
  constexpr int KS = K / 32;
  int wave = threadIdx.x >> 6;
  int lane = threadIdx.x & 63;
  int row0 = (gblock * 4 + wave) * 16;
  if (row0 >= n_rows) return;

  int lrow = lane & 15;
  int lk = (lane >> 4) * 8;

  short8 bfrag[KS][4];
#pragma unroll
  for (int ks = 0; ks < KS; ++ks)
#pragma unroll
    for (int nt = 0; nt < 4; ++nt) {
      short8 b;
#pragma unroll
      for (int j = 0; j < 8; ++j)
        b[j] = f2bf(W[(size_t)(ks * 32 + lk + j) * 64 + nt * 16 + lrow]);
      bfrag[ks][nt] = b;
    }

  int row = row0 + lrow;
  f32x4 acc[4] = {};
#pragma unroll
  for (int ks = 0; ks < KS; ++ks) {
    short8 a;
    const float* ip = in_ + (size_t)row * K + ks * 32 + lk;
    f32x4 v0 = *(const f32x4*)(ip);
    f32x4 v1 = *(const f32x4*)(ip + 4);
#pragma unroll
    for (int j = 0; j < 4; ++j) {
      a[j] = f2bf(v0[j]);
      a[4 + j] = f2bf(v1[j]);
    }
#pragma unroll
    for (int nt = 0; nt < 4; ++nt)
      acc[nt] = __builtin_amdgcn_mfma_f32_16x16x32_bf16(a, bfrag[ks][nt],
                                                        acc[nt], 0, 0, 0);
  }

  int crow = row0 + (lane >> 4) * 4;
#pragma unroll
  for (int nt = 0; nt < 4; ++nt) {
    int ocol = nt * 16 + lrow;
#pragma unroll
    for (int r = 0; r < 4; ++r)
      out_[(size_t)(crow + r) * 64 + ocol] = f32_to_fp8_hw(acc[nt][r]);
  }
}

// ---------------------------------------------------------------------------
// Fused: blocks [0, NCHUNK) = bucket histogram (LDS int atomics);
// blocks [NCHUNK, +gemm_grid) = GEMM1 (x@W1 -> hA fp8). Independent.
// ---------------------------------------------------------------------------
__global__ __launch_bounds__(256) void hist_gemm1_kernel(
    const int* __restrict__ dst, int* __restrict__ countsT,
    const float* __restrict__ x, const float* __restrict__ W1,
    unsigned char* __restrict__ hA, int n_rows) {
  __shared__ int lhist[NB_BUCK];
  int b = (int)blockIdx.x;
  if (b >= NCHUNK) {
    gemm64_body<128>(b - NCHUNK, x, W1, hA, n_rows);
    return;
  }
  for (int i = threadIdx.x; i < NB_BUCK; i += 256) lhist[i] = 0;
  __syncthreads();
  int beg = b * CHH, end = beg + CHH;
  for (int i = beg + (int)threadIdx.x; i < end; i += 256)
    atomicAdd(&lhist[((unsigned)dst[i]) >> BUCK_SH], 1);
  __syncthreads();
  for (int bb = threadIdx.x; bb < NB_BUCK; bb += 256)
    countsT[bb * NCHUNK + b] = lhist[bb];
}

// K1: per-bucket exclusive scan over NCHUNK=256 chunk counts (+ total).
__global__ __launch_bounds__(256) void scan_buckets_kernel(
    int* __restrict__ countsT, int* __restrict__ btot) {
  int b = blockIdx.x * 4 + (threadIdx.x >> 6);
  int lane = threadIdx.x & 63;
  if (b >= NB_BUCK) return;
  int4 v = *(const int4*)(countsT + b * NCHUNK + lane * 4);
  int s = v.x + v.y + v.z + v.w;
  int incl = s;
#pragma unroll
  for (int d = 1; d < 64; d <<= 1) {
    int t = __shfl_up(incl, d, 64);
    if (lane >= d) incl += t;
  }
  int excl = incl - s;
  int4 o;
  o.x = excl;
  o.y = excl + v.x;
  o.z = o.y + v.y;
  o.w = o.z + v.z;
  *(int4*)(countsT + b * NCHUNK + lane * 4) = o;
  if (lane == 63) btot[b] = incl;
}

// K2: exclusive scan of bucket totals -> bstart[0..NB_BUCK].
__global__ __launch_bounds__(1024) void scan_btot_kernel(
    const int* __restrict__ btot, int* __restrict__ bstart) {
  __shared__ int lds[1024];
  int t = threadIdx.x;
  int v = (t < NB_BUCK) ? btot[t] : 0;
  lds[t] = v;
  __syncthreads();
  for (int off = 1; off < 1024; off <<= 1) {
    int tv = (t >= off) ? lds[t - off] : 0;
    __syncthreads();
    lds[t] += tv;
    __syncthreads();
  }
  if (t < NB_BUCK) bstart[t] = lds[t] - v;
  if (t == NB_BUCK - 1) bstart[NB_BUCK] = lds[t];
}

// ---------------------------------------------------------------------------
// Partition (standalone, WIDE): 128 blocks x 1024 threads.
// ---------------------------------------------------------------------------
__global__ __launch_bounds__(1024) void partition_kernel(
    const int* __restrict__ src, const int* __restrict__ dst,
    const int* __restrict__ offs /* countsT after K1 */,
    const int* __restrict__ bstart, unsigned* __restrict__ packed) {
  __shared__ int cur[NB_BUCK];
  int b = (int)blockIdx.x;
  for (int bb = threadIdx.x; bb < NB_BUCK; bb += 1024)
    cur[bb] = bstart[bb] + offs[bb * NCHUNK + 2 * b];
  __syncthreads();
  int beg = b * CHP, end = beg + CHP;
  for (int i = beg + (int)threadIdx.x; i < end; i += 1024) {
    int d = dst[i];
    int s = src[i];
    int bb = ((unsigned)d) >> BUCK_SH;
    int pos = atomicAdd(&cur[bb], 1);
    packed[pos] = ((unsigned)(d & (BUCK_NODES - 1)) << 17) | (unsigned)s;
  }
}

// ---------------------------------------------------------------------------
// Per-bucket counting sort -> dst-sorted col[] + row_ptr[] (global CSR).
// ---------------------------------------------------------------------------
__global__ __launch_bounds__(256) void sort_bucket_kernel(
    const unsigned* __restrict__ packed, const int* __restrict__ bstart,
    int* __restrict__ col, int* __restrict__ row_ptr, int n_nodes,
    int n_edges) {
  __shared__ int lhist[BUCK_NODES];
  __shared__ int lcur[BUCK_NODES];
  __shared__ int wsum0;
  int b = (int)blockIdx.x;
  int beg = bstart[b], end = bstart[b + 1];
  int t = (int)threadIdx.x;

  if (t < BUCK_NODES) lhist[t] = 0;
  __syncthreads();
  for (int e = beg + t; e < end; e += 256)
    atomicAdd(&lhist[packed[e] >> 17], 1);
  __syncthreads();

  int v = 0, incl = 0;
  if (t < BUCK_NODES) {
    v = lhist[t];
    incl = v;
#pragma unroll
    for (int d = 1; d < 64; d <<= 1) {
      int u = __shfl_up(incl, d, 64);
      if ((t & 63) >= d) incl += u;
    }
  }
  if (t == 63) wsum0 = incl;
  __syncthreads();
  if (t >= 64 && t < BUCK_NODES) incl += wsum0;
  if (t < BUCK_NODES) {
    int excl = incl - v;
    lcur[t] = excl;
    int node = b * BUCK_NODES + t;
    if (node < n_nodes) row_ptr[node] = beg + excl;
  }
  if (b == NB_BUCK - 1 && t == 0) row_ptr[n_nodes] = n_edges;
  __syncthreads();

  for (int e = beg + t; e < end; e += 256) {
    unsigned pe = packed[e];
    int ld = (int)(pe >> 17);
    int pos = beg + atomicAdd(&lcur[ld], 1);
    col[pos] = (int)(pe & 0x1FFFFu);
  }
}

// ---------------------------------------------------------------------------
// Split-wave dual-node agg inner: lanes 0-31 = node A, 32-63 = node B.
// Per half: slot = (lane>>2)&7 (8 edge slots), q = lane&3 (16 fp8 ch each).
// Lane loads uint4 (16B); 1 gather instruction serves 8 edges per half
// (16 per wave). Packed f32 accumulation (v_pk_add_f32) halves add count.
// acc[i] holds channels q*16 + {2i, 2i+1}. Reduce: xor 4, 8, 16 (in-half).
// ---------------------------------------------------------------------------
__device__ __forceinline__ void agg_node_dual(
    const unsigned char* __restrict__ h, const int* __restrict__ col, int beg,
    int end, int slot, int q, f32x2* acc) {
  f32x2 tacc[8];
#pragma unroll
  for (int i = 0; i < 8; ++i) {
    acc[i] = 0.f;
    tacc[i] = 0.f;
  }
  int e = beg + slot;
  for (; e + 8 < end; e += 16) {
    int sa = col[e];
    int sb = col[e + 8];
    uint4 ua = *(const uint4*)(h + (size_t)sa * 64 + q * 16);
    uint4 ub = *(const uint4*)(h + (size_t)sb * 64 + q * 16);
    acc[0] += __builtin_amdgcn_cvt_pk_f32_fp8((int)ua.x, false);
    acc[1] += __builtin_amdgcn_cvt_pk_f32_fp8((int)ua.x, true);
    acc[2] += __builtin_amdgcn_cvt_pk_f32_fp8((int)ua.y, false);
    acc[3] += __builtin_amdgcn_cvt_pk_f32_fp8((int)ua.y, true);
    acc[4] += __builtin_amdgcn_cvt_pk_f32_fp8((int)ua.z, false);
    acc[5] += __builtin_amdgcn_cvt_pk_f32_fp8((int)ua.z, true);
    acc[6] += __builtin_amdgcn_cvt_pk_f32_fp8((int)ua.w, false);
    acc[7] += __builtin_amdgcn_cvt_pk_f32_fp8((int)ua.w, true);
    tacc[0] += __builtin_amdgcn_cvt_pk_f32_fp8((int)ub.x, false);
    tacc[1] += __builtin_amdgcn_cvt_pk_f32_fp8((int)ub.x, true);
    tacc[2] += __builtin_amdgcn_cvt_pk_f32_fp8((int)ub.y, false);
    tacc[3] += __builtin_amdgcn_cvt_pk_f32_fp8((int)ub.y, true);
    tacc[4] += __builtin_amdgcn_cvt_pk_f32_fp8((int)ub.z, false);
    tacc[5] += __builtin_amdgcn_cvt_pk_f32_fp8((int)ub.z, true);
    tacc[6] += __builtin_amdgcn_cvt_pk_f32_fp8((int)ub.w, false);
    tacc[7] += __builtin_amdgcn_cvt_pk_f32_fp8((int)ub.w, true);
  }
  for (; e < end; e += 8) {
    int sa = col[e];
    uint4 ua = *(const uint4*)(h + (size_t)sa * 64 + q * 16);
    acc[0] += __builtin_amdgcn_cvt_pk_f32_fp8((int)ua.x, false);
    acc[1] += __builtin_amdgcn_cvt_pk_f32_fp8((int)ua.x, true);
    acc[2] += __builtin_amdgcn_cvt_pk_f32_fp8((int)ua.y, false);
    acc[3] += __builtin_amdgcn_cvt_pk_f32_fp8((int)ua.y, true);
    acc[4] += __builtin_amdgcn_cvt_pk_f32_fp8((int)ua.z, false);
    acc[5] += __builtin_amdgcn_cvt_pk_f32_fp8((int)ua.z, true);
    acc[6] += __builtin_amdgcn_cvt_pk_f32_fp8((int)ua.w, false);
    acc[7] += __builtin_amdgcn_cvt_pk_f32_fp8((int)ua.w, true);
  }
#pragma unroll
  for (int i = 0; i < 8; ++i) acc[i] += tacc[i];
#pragma unroll
  for (int d = 4; d <= 16; d <<= 1) {
#pragma unroll
    for (int i = 0; i < 8; ++i) {
      acc[i][0] += __shfl_xor(acc[i][0], d);
      acc[i][1] += __shfl_xor(acc[i][1], d);
    }
  }
}

// ---------------------------------------------------------------------------
// Fused agg + bias + ReLU + (row @ W) -> fp8. Block = 16 nodes, 4 waves;
// each wave processes 2 nodes concurrently (split halves) x 2 sequentially.
// ---------------------------------------------------------------------------
__global__ __launch_bounds__(256) void agg_gemm_kernel(
    const unsigned char* __restrict__ h, const int* __restrict__ row_ptr,
    const int* __restrict__ col, const float* __restrict__ bias,
    const float* __restrict__ W, unsigned char* __restrict__ outg,
    int n_nodes) {
  __shared__ float rowbuf[16][68];
  int wid = threadIdx.x >> 6;
  int lane = threadIdx.x & 63;
  int half = lane >> 5;
  int slot = (lane >> 2) & 7;
  int q = lane & 3;
  int nbase = blockIdx.x * 16;

#pragma unroll
  for (int n = 0; n < 2; ++n) {
    int ln = wid * 4 + n * 2 + half;
    int node = nbase + ln;
    f32x2 acc[8];
    agg_node_dual(h, col, row_ptr[node], row_ptr[node + 1], slot, q, acc);
    if ((lane & 31) < 4) {
#pragma unroll
      for (int wv = 0; wv < 4; ++wv) {
        f32x4 r;
        r[0] = fmaxf(acc[2 * wv][0] + bias[q * 16 + wv * 4 + 0], 0.f);
        r[1] = fmaxf(acc[2 * wv][1] + bias[q * 16 + wv * 4 + 1], 0.f);
        r[2] = fmaxf(acc[2 * wv + 1][0] + bias[q * 16 + wv * 4 + 2], 0.f);
        r[3] = fmaxf(acc[2 * wv + 1][1] + bias[q * 16 + wv * 4 + 3], 0.f);
        *(f32x4*)&rowbuf[ln][q * 16 + wv * 4] = r;
      }
    }
  }
  __syncthreads();

  int lrow = lane & 15;
  int lk = (lane >> 4) * 8;
  f32x4 acc2 = {};
#pragma unroll
  for (int ks = 0; ks < 2; ++ks) {
    short8 a, bv;
#pragma unroll
    for (int j = 0; j < 8; ++j) a[j] = f2bf(rowbuf[lrow][ks * 32 + lk + j]);
#pragma unroll
    for (int j = 0; j < 8; ++j)
      bv[j] = f2bf(W[(size_t)(ks * 32 + lk + j) * 64 + wid * 16 + lrow]);
    acc2 = __builtin_amdgcn_mfma_f32_16x16x32_bf16(a, bv, acc2, 0, 0, 0);
  }
  int crow = (lane >> 4) * 4;
#pragma unroll
  for (int r = 0; r < 4; ++r)
    outg[(size_t)(nbase + crow + r) * 64 + wid * 16 + lrow] =
        f32_to_fp8_hw(acc2[r]);
}

// ---------------------------------------------------------------------------
// Final agg + bias + ReLU (fp32 out). 2 nodes per wave, 8 per block.
// ---------------------------------------------------------------------------
__global__ __launch_bounds__(256) void agg_final_kernel(
    const unsigned char* __restrict__ h, const int* __restrict__ row_ptr,
    const int* __restrict__ col, const float* __restrict__ bias,
    float* __restrict__ out, int n_nodes) {
  int wid = threadIdx.x >> 6;
  int lane = threadIdx.x & 63;
  int half = lane >> 5;
  int slot = (lane >> 2) & 7;
  int q = lane & 3;
  int node = blockIdx.x * 8 + wid * 2 + half;
  int beg = 0, end = 0;
  if (node < n_nodes) {
    beg = row_ptr[node];
    end = row_ptr[node + 1];
  }
  f32x2 acc[8];
  agg_node_dual(h, col, beg, end, slot, q, acc);
  if (node < n_nodes && (lane & 31) < 4) {
#pragma unroll
    for (int wv = 0; wv < 4; ++wv) {
      f32x4 r;
      r[0] = fmaxf(acc[2 * wv][0] + bias[q * 16 + wv * 4 + 0], 0.f);
      r[1] = fmaxf(acc[2 * wv][1] + bias[q * 16 + wv * 4 + 1], 0.f);
      r[2] = fmaxf(acc[2 * wv + 1][0] + bias[q * 16 + wv * 4 + 2], 0.f);
      r[3] = fmaxf(acc[2 * wv + 1][1] + bias[q * 16 + wv * 4 + 3], 0.f);
      *((f32x4*)out + (size_t)node * 16 + q * 4 + wv) = r;
    }
  }
}

extern "C" void kernel_launch(void* const* d_in, const int* in_sizes, int n_in,
                              void* d_out, int out_size, void* d_ws,
                              size_t ws_size, hipStream_t stream) {
  const float* x = (const float*)d_in[0];
  const int* src = (const int*)d_in[1];
  const int* dst = (const int*)d_in[2];
  const float* W1 = (const float*)d_in[3];
  const float* b1 = (const float*)d_in[4];
  const float* W2 = (const float*)d_in[5];
  const float* b2 = (const float*)d_in[6];
  const float* W3 = (const float*)d_in[7];
  const float* b3 = (const float*)d_in[8];
  float* out = (float*)d_out;

  const int N = N_NODES_C;
  const int E = N_EDGES_C;

  // Workspace layout (31 MB), as round 13.
  char* ws = (char*)d_ws;
  int* countsT = (int*)(ws + 0);
  int* btot = (int*)(ws + (1u << 20));
  int* bstart = (int*)(ws + (1u << 20) + (16u << 10));
  int* row_ptr = (int*)(ws + (2u << 20));
  unsigned* packed = (unsigned*)(ws + (3u << 20));
  int* col = (int*)(ws + (10u << 20));
  unsigned char* hA = (unsigned char*)(ws + (17u << 20));
  unsigned char* hB = (unsigned char*)(ws + (24u << 20));

  const int gemm_grid = (N + 63) / 64;  // 1563
  const int k1_grid = (NB_BUCK + 3) / 4;
  const int aggg_grid = N / 16;         // 6250
  const int aggf_grid = (N + 7) / 8;    // 12500

  // ---- CSR build; gemm1 overlapped with hist; wide partition ----
  hist_gemm1_kernel<<<NCHUNK + gemm_grid, 256, 0, stream>>>(dst, countsT, x,
                                                            W1, hA, N);
  scan_buckets_kernel<<<k1_grid, 256, 0, stream>>>(countsT, btot);
  scan_btot_kernel<<<1, 1024, 0, stream>>>(btot, bstart);
  partition_kernel<<<NPART, 1024, 0, stream>>>(src, dst, countsT, bstart,
                                               packed);
  sort_bucket_kernel<<<NB_BUCK, 256, 0, stream>>>(packed, bstart, col, row_ptr,
                                                  N, E);

  // ---- Layer 1 agg fused with gemm2: hB = fp8(relu(agg(hA)+b1) @ W2) ----
  agg_gemm_kernel<<<aggg_grid, 256, 0, stream>>>(hA, row_ptr, col, b1, W2, hB,
                                                 N);
  // ---- Layer 2 agg fused with gemm3: hA = fp8(relu(agg(hB)+b2) @ W3) ----
  agg_gemm_kernel<<<aggg_grid, 256, 0, stream>>>(hB, row_ptr, col, b2, W3, hA,
                                                 N);
  // ---- Layer 3 final: out = relu(agg(hA)+b3) (fp32) ----
  agg_final_kernel<<<aggf_grid, 256, 0, stream>>>(hA, row_ptr, col, b3, out, N);
}